// Round 11
// baseline (52.443 us; speedup 1.0000x reference)
//
#include <hip/hip_runtime.h>
#include <math.h>

#define SRATE   16000
#define FLEN    400
#define STEP    160
#define NFFT    512
#define NBINS   257
#define NFILT   26
#define NUMCEP  13
#define BATCH   64
#define TLEN    320000
#define NFRAMES 1999
#define EPSF    1.1920929e-07f
#define PI_F    3.14159265358979323846f

#define GRID_MAIN 8000

typedef float    v2f __attribute__((ext_vector_type(2)));
typedef unsigned uv2 __attribute__((ext_vector_type(2)));

__device__ __forceinline__ v2f mk2(float a, float b) { v2f v; v.x = a; v.y = b; return v; }
__device__ __forceinline__ v2f pfma(v2f a, v2f b, v2f c) { return __builtin_elementwise_fma(a, b, c); }

// pack two f32 -> 2xbf16 (round-to-nearest-ish), and unpack
__device__ __forceinline__ unsigned pkbf(float a, float b) {
    unsigned ua = __builtin_bit_cast(unsigned, a);
    unsigned ub = __builtin_bit_cast(unsigned, b);
    return ((ua + 0x8000u) >> 16) | ((ub + 0x8000u) & 0xFFFF0000u);
}
__device__ __forceinline__ v2f unpkbf(unsigned u) {
    return mk2(__builtin_bit_cast(float, u << 16),
               __builtin_bit_cast(float, u & 0xFFFF0000u));
}

template<int CTRL>
__device__ __forceinline__ float fdpp(float x) {   // DPP: VALU pipe
    return __builtin_bit_cast(float, __builtin_amdgcn_mov_dpp(
        __builtin_bit_cast(int, x), CTRL, 0xF, 0xF, true));
}
template<int IMM>
__device__ __forceinline__ float fswz(float x) {   // ds_swizzle: DS pipe
    return __builtin_bit_cast(float, __builtin_amdgcn_ds_swizzle(
        __builtin_bit_cast(int, x), IMM));
}
__device__ __forceinline__ uv2 pl32(float x) {     // permlane32_swap: VALU pipe
    unsigned u = __builtin_bit_cast(unsigned, x);
    return __builtin_amdgcn_permlane32_swap(u, u, false, false);
}
__device__ __forceinline__ float fxor32(float x, bool hi32) {
    uv2 r = pl32(x);
    return __builtin_bit_cast(float, hi32 ? r[0] : r[1]);
}
#if __has_builtin(__builtin_amdgcn_permlane16_swap)
__device__ __forceinline__ float fxor16(float x, bool hi16) {  // VALU pipe
    unsigned u = __builtin_bit_cast(unsigned, x);
    uv2 r = __builtin_amdgcn_permlane16_swap(u, u, false, false);
    return __builtin_bit_cast(float, hi16 ? r[0] : r[1]);
}
#define SH_X16(v) fxor16(v, hi_)
#else
#define SH_X16(v) fswz<0x401F>(v)
#endif

#define DPP_X1   0xB1
#define DPP_X2   0x4E
#define DPP_X8   0x128
#define SWZ_X4   0x101F
#define SWZ_X16  0x401F

// ws layout (int-indexed): bins[0..31] | dct f32 [32..369] | qoff[370..434] | doff[440..504]
#define WS_DCT  32
#define WS_QOFF 370
#define WS_DOFF 440

// ---------------------------------------------------------------------------
// Setup: mel bins (f64), lifted DCT (f64), nframes output, live-quad prefix
// qoff[65], dead-frame prefix doff[65].
// ---------------------------------------------------------------------------
__global__ void mfcc_setup_kernel(const int* __restrict__ lengths,
                                  void* __restrict__ ws,
                                  float* __restrict__ out_nframes) {
    int tid = threadIdx.x;           // 64 threads = 1 wave
    int*   bins = (int*)ws;
    float* dctw = (float*)ws + WS_DCT;
    int*   qoff = (int*)ws + WS_QOFF;
    int*   doff = (int*)ws + WS_DOFF;

    if (tid < 28) {
        double M    = 2595.0 * log10(1.0 + 8000.0 / 700.0);
        double step = M / 27.0;
        double mel  = (tid == 27) ? M : (double)tid * step;
        double hz   = 700.0 * (pow(10.0, mel / 2595.0) - 1.0);
        bins[tid] = (int)floor((double)(NFFT + 1) * hz / (double)SRATE);
    }
    for (int t = tid; t < NUMCEP * NFILT; t += 64) {
        int k = t / NFILT, j = t - k * NFILT;
        double v = cos(M_PI * (double)((2 * j + 1) * k) / (2.0 * (double)NFILT));
        v *= (k == 0) ? 1.0 / sqrt((double)NFILT) : sqrt(2.0 / (double)NFILT);
        double lift = 1.0 + 11.0 * sin(M_PI * (double)k / 22.0);
        dctw[t] = (float)(v * lift);
    }
    {
        int len = lengths[tid];
        int nf  = (len <= FLEN) ? 1 : 1 + (len - FLEN + STEP - 1) / STEP;
        out_nframes[tid] = (float)nf;
        int x = (nf + 3) >> 2;                       // live quads for this b
        int d = NFRAMES - nf;                        // dead frames for this b
        #pragma unroll
        for (int off = 1; off < 64; off <<= 1) {
            int y  = __shfl_up(x, off);
            int y2 = __shfl_up(d, off);
            if (tid >= off) { x += y; d += y2; }
        }
        qoff[tid + 1] = x;
        doff[tid + 1] = d;
        if (tid == 0) { qoff[0] = 0; doff[0] = 0; }
    }
}

// ---------------------------------------------------------------------------
// Main kernel: one wave per LIVE frame quad (compacted); dead blocks zero-fill
// the dead ceps region. pspec stored as packed 2xbf16 -> LDS ~11.6 KB/block
// so occupancy is no longer LDS-capped (latency-hiding TLP doubles).
// ---------------------------------------------------------------------------
__global__ __launch_bounds__(256)
void mfcc_kernel(const float* __restrict__ sig,
                 const int*   __restrict__ lengths,
                 const void*  __restrict__ ws,
                 float*       __restrict__ out) {
    __shared__ unsigned psA[4][260];     // pair0 pspec, 2xbf16 per bin
    __shared__ unsigned psB[4][260];     // pair1 pspec
    __shared__ v2f featAs[4][28], featBs[4][28];
    __shared__ float dctS[NUMCEP * NFILT];
    __shared__ int   binsS[NFILT + 2];

    const int tid  = threadIdx.x;
    const int lane = tid & 63;
    const int w    = tid >> 6;

    const int* qoffG = (const int*)ws + WS_QOFF;
    const int total = qoffG[64];

    // ---- dead block: zero-fill the dead ceps region, then exit ----
    if ((int)blockIdx.x * 4 >= total) {
        const int* doffG = (const int*)ws + WS_DOFF;
        const int liveBlocks = (total + 3) >> 2;
        const int deadFrames = doffG[64];
        const long deadFloats = (long)deadFrames * NUMCEP;
        const long stride = (long)(GRID_MAIN - liveBlocks) * 256;
        for (long idx = (long)(blockIdx.x - liveBlocks) * 256 + tid;
             idx < deadFloats; idx += stride) {
            int F = (int)(idx / 13);
            int k = (int)(idx - 13L * F);
            int lo = 0, hi = 64;
            #pragma unroll
            for (int it = 0; it < 6; ++it) {
                int mid = (lo + hi) >> 1;
                if (doffG[mid] <= F) lo = mid; else hi = mid;
            }
            int nf2 = NFRAMES - (doffG[lo + 1] - doffG[lo]);
            int f   = nf2 + (F - doffG[lo]);
            out[((long)lo * NFRAMES + f) * NUMCEP + k] = 0.0f;
        }
        return;
    }

    {
        const int*   binsG = (const int*)ws;
        const float* dctG  = (const float*)ws + WS_DCT;
        for (int t = tid; t < NUMCEP * NFILT; t += 256) dctS[t] = dctG[t];
        if (tid < NFILT + 2) binsS[tid] = binsG[tid];
    }
    __syncthreads();

    // ---- dense live index -> (b, q) via ballot search ----
    const int L = blockIdx.x * 4 + w;
    if (L >= total) return;                          // partial tail block
    int qv = qoffG[lane];
    unsigned long long mm = __ballot(qv <= L);
    const int b  = __popcll(mm) - 1;
    const int q  = L - qoffG[b];
    const int f0 = 4 * q;
    const int len = lengths[b];
    const int nf  = (len <= FLEN) ? 1 : 1 + (len - FLEN + STEP - 1) / STEP;

    const float* s = sig + (long)b * TLEN;
    const int base = f0 * STEP;

    const int B   = (int)(__brev((unsigned)lane) >> 26);   // brev6
    const int i0  = 8 * B;
    const bool liveB = (i0 < FLEN);

    // ---- load + pre-emphasis + mask -> two packed FFT states ----
    v2f Zr0[4], Zi0[4], Zr1[4], Zi1[4];
    const bool fastw = (base >= 1) && (base + 880 <= len);
    if (fastw) {
        float w0[9], w1[9], w2[9], w3[9];
        if (liveB) {
            const float4* sv = (const float4*)(s + base + i0);
            float4 a0 = sv[-1],  a1 = sv[0],   a2 = sv[1];
            float4 b0 = sv[39],  b1 = sv[40],  b2 = sv[41];
            float4 c0 = sv[79],  c1 = sv[80],  c2 = sv[81];
            float4 d0 = sv[119], d1 = sv[120], d2 = sv[121];
#define UNPK(W, q0, q1, q2)                                                   \
            W[0] = q0.w; W[1] = q1.x; W[2] = q1.y; W[3] = q1.z; W[4] = q1.w;  \
            W[5] = q2.x; W[6] = q2.y; W[7] = q2.z; W[8] = q2.w;
            UNPK(w0, a0, a1, a2)
            UNPK(w1, b0, b1, b2)
            UNPK(w2, c0, c1, c2)
            UNPK(w3, d0, d1, d2)
#undef UNPK
        } else {
            #pragma unroll
            for (int j = 0; j < 9; ++j) { w0[j] = w1[j] = w2[j] = w3[j] = 0.0f; }
        }
        #pragma unroll
        for (int m = 0; m < 4; ++m) {
            const int j = (m == 0) ? 0 : (m == 1) ? 4 : (m == 2) ? 2 : 6;  // brev3
            Zr0[m] = mk2(fmaf(-0.97f, w0[j],     w0[j + 1]),
                         fmaf(-0.97f, w0[j + 1], w0[j + 2]));
            Zi0[m] = mk2(fmaf(-0.97f, w1[j],     w1[j + 1]),
                         fmaf(-0.97f, w1[j + 1], w1[j + 2]));
            Zr1[m] = mk2(fmaf(-0.97f, w2[j],     w2[j + 1]),
                         fmaf(-0.97f, w2[j + 1], w2[j + 2]));
            Zi1[m] = mk2(fmaf(-0.97f, w3[j],     w3[j + 1]),
                         fmaf(-0.97f, w3[j + 1], w3[j + 2]));
        }
    } else {
        float w0[9], w1[9], w2[9], w3[9];
        const int tb0 = base + i0 - 1;
        #pragma unroll
        for (int j = 0; j < 9; ++j) {
            int t0 = tb0 + j;
            w0[j] = (liveB && t0 >= 0 && t0 < len) ? s[t0] : 0.0f;
            int t1 = t0 + 160; w1[j] = (liveB && t1 < len) ? s[t1] : 0.0f;
            int t2 = t0 + 320; w2[j] = (liveB && t2 < len) ? s[t2] : 0.0f;
            int t3 = t0 + 480; w3[j] = (liveB && t3 < len) ? s[t3] : 0.0f;
        }
        const int tbe = base + i0;
        #pragma unroll
        for (int m = 0; m < 4; ++m) {
            const int j = (m == 0) ? 0 : (m == 1) ? 4 : (m == 2) ? 2 : 6;
#define ASMW(Wk, OFF, DST)                                                    \
            { float va = fmaf(-0.97f, Wk[j],     Wk[j + 1]);                  \
              float vb = fmaf(-0.97f, Wk[j + 1], Wk[j + 2]);                  \
              bool ma = liveB && (tbe + (OFF) + j)     < len;                 \
              bool mb = liveB && (tbe + (OFF) + j + 1) < len;                 \
              DST = mk2(ma ? va : 0.0f, mb ? vb : 0.0f); }
            ASMW(w0, 0,   Zr0[m])
            ASMW(w1, 160, Zi0[m])
            ASMW(w2, 320, Zr1[m])
            ASMW(w3, 480, Zi1[m])
#undef ASMW
        }
    }

    // ---- per-lane twiddles (shared by both FFTs) ----
    const float ang = -PI_F * (float)lane / 256.0f;
    float T1i = __sinf(ang);
    float T1r = __cosf(ang);
#define SQC(orr, oii, ir, ii) { float _r = ir * ir - ii * ii; oii = 2.0f * ir * ii; orr = _r; }
    float T2r, T2i;   SQC(T2r, T2i, T1r, T1i)
    float T4r, T4i;   SQC(T4r, T4i, T2r, T2i)
    float T8r, T8i;   SQC(T8r, T8i, T4r, T4i)
    float T16r, T16i; SQC(T16r, T16i, T8r, T8i)
    float T32r, T32i; SQC(T32r, T32i, T16r, T16i)
    float T64r, T64i; SQC(T64r, T64i, T32r, T32i)
    float T128r, T128i; SQC(T128r, T128i, T64r, T64i)
    const float RH = 0.70710678118654752f;
    const float A1r = RH * (T1r + T1i), A1i = RH * (T1i - T1r);
    const float A2r = T1i,              A2i = -T1r;
    const float A3r = RH * (T1i - T1r), A3i = -RH * (T1r + T1i);

    // ---- cross-lane stage d=1 (both FFTs, interleaved per m) ----
    {
        const float sg = (lane & 1) ? -1.0f : 1.0f;
        const v2f sg2 = mk2(sg, sg);
        #pragma unroll
        for (int m = 0; m < 4; ++m) {
            v2f pr0 = mk2(fdpp<DPP_X1>(Zr0[m].x), fdpp<DPP_X1>(Zr0[m].y));
            v2f pi0 = mk2(fdpp<DPP_X1>(Zi0[m].x), fdpp<DPP_X1>(Zi0[m].y));
            v2f pr1 = mk2(fdpp<DPP_X1>(Zr1[m].x), fdpp<DPP_X1>(Zr1[m].y));
            v2f pi1 = mk2(fdpp<DPP_X1>(Zi1[m].x), fdpp<DPP_X1>(Zi1[m].y));
            Zr0[m] = pfma(sg2, Zr0[m], pr0);
            Zi0[m] = pfma(sg2, Zi0[m], pi0);
            Zr1[m] = pfma(sg2, Zr1[m], pr1);
            Zi1[m] = pfma(sg2, Zi1[m], pi1);
        }
    }

    // ---- cross-lane stages d = 2..32 (both FFTs interleaved per m) ----
#define PK_XSTAGE2(d, UR, UI, SH)                                             \
    {                                                                         \
        const bool hi_ = (lane & (d)) != 0;                                   \
        const float ur = hi_ ? (UR) : 1.0f;                                   \
        const float ui = hi_ ? (UI) : 0.0f;                                   \
        const float sg = hi_ ? 1.0f : -1.0f;                                  \
        const v2f ur2 = mk2(ur, ur), ui2 = mk2(ui, ui);                       \
        const v2f nui2 = mk2(-ui, -ui), sg2 = mk2(sg, sg);                    \
        _Pragma("unroll")                                                     \
        for (int m = 0; m < 4; ++m) {                                         \
            v2f tr0 = pfma(Zi0[m], nui2, Zr0[m] * ur2);                       \
            v2f ti0 = pfma(Zi0[m], ur2,  Zr0[m] * ui2);                       \
            v2f tr1 = pfma(Zi1[m], nui2, Zr1[m] * ur2);                       \
            v2f ti1 = pfma(Zi1[m], ur2,  Zr1[m] * ui2);                       \
            v2f pr0 = mk2(SH(tr0.x), SH(tr0.y));                              \
            v2f pi0 = mk2(SH(ti0.x), SH(ti0.y));                              \
            v2f pr1 = mk2(SH(tr1.x), SH(tr1.y));                              \
            v2f pi1 = mk2(SH(ti1.x), SH(ti1.y));                              \
            Zr0[m] = pfma(sg2, pr0, tr0);                                     \
            Zi0[m] = pfma(sg2, pi0, ti0);                                     \
            Zr1[m] = pfma(sg2, pr1, tr1);                                     \
            Zi1[m] = pfma(sg2, pi1, ti1);                                     \
        }                                                                     \
    }
#define SH_X2(v)  fdpp<DPP_X2>(v)
#define SH_X4(v)  fswz<SWZ_X4>(v)
#define SH_X8(v)  fdpp<DPP_X8>(v)
#define SH_X32(v) fxor32(v, hi_)
    PK_XSTAGE2(2,  T128r, T128i, SH_X2)
    PK_XSTAGE2(4,  T64r,  T64i,  SH_X4)
    PK_XSTAGE2(8,  T32r,  T32i,  SH_X8)
    PK_XSTAGE2(16, T16r,  T16i,  SH_X16)
    PK_XSTAGE2(32, T8r,   T8i,   SH_X32)

    // ---- in-register stages d=64, d=128 (both FFTs) ----
#define PBFLY2(A, Bv, WR, WI)                                                 \
    {                                                                         \
        const v2f wr2 = mk2((WR), (WR)), wi2 = mk2((WI), (WI));               \
        const v2f nwi2 = mk2(-(WI), -(WI));                                   \
        v2f tr0 = pfma(Zi0[Bv], nwi2, Zr0[Bv] * wr2);                         \
        v2f ti0 = pfma(Zi0[Bv], wr2,  Zr0[Bv] * wi2);                         \
        v2f tr1 = pfma(Zi1[Bv], nwi2, Zr1[Bv] * wr2);                         \
        v2f ti1 = pfma(Zi1[Bv], wr2,  Zr1[Bv] * wi2);                         \
        Zr0[Bv] = Zr0[A] - tr0;  Zi0[Bv] = Zi0[A] - ti0;                      \
        Zr0[A]  = Zr0[A] + tr0;  Zi0[A]  = Zi0[A] + ti0;                      \
        Zr1[Bv] = Zr1[A] - tr1;  Zi1[Bv] = Zi1[A] - ti1;                      \
        Zr1[A]  = Zr1[A] + tr1;  Zi1[A]  = Zi1[A] + ti1;                      \
    }
    PBFLY2(0, 1, T4r, T4i)
    PBFLY2(2, 3, T4r, T4i)
    PBFLY2(0, 2, T2r, T2i)
    PBFLY2(1, 3, T2i, -T2r)

    // ---- final stage d=256 (both FFTs) ----
    float zrA[8], ziA[8], zrB[8], ziB[8];
    #pragma unroll
    for (int m = 0; m < 4; ++m) {
        const float Wr = (m == 0) ? T1r : (m == 1) ? A1r : (m == 2) ? A2r : A3r;
        const float Wi = (m == 0) ? T1i : (m == 1) ? A1i : (m == 2) ? A2i : A3i;
        { float tr = Zr0[m].y * Wr - Zi0[m].y * Wi;
          float ti = Zr0[m].y * Wi + Zi0[m].y * Wr;
          zrA[m]     = Zr0[m].x + tr;  ziA[m]     = Zi0[m].x + ti;
          zrA[m + 4] = Zr0[m].x - tr;  ziA[m + 4] = Zi0[m].x - ti; }
        { float tr = Zr1[m].y * Wr - Zi1[m].y * Wi;
          float ti = Zr1[m].y * Wi + Zi1[m].y * Wr;
          zrB[m]     = Zr1[m].x + tr;  ziB[m]     = Zi1[m].x + ti;
          zrB[m + 4] = Zr1[m].x - tr;  ziB[m + 4] = Zi1[m].x - ti; }
    }

    // ---- unpack 2x2 real spectra + power + energy (pspec -> 2xbf16 LDS) ----
    unsigned* PA = psA[w];
    unsigned* PB = psB[w];
    const float inv = 1.0f / (4.0f * (float)NFFT);
    v2f eA = mk2(0.0f, 0.0f), eB = mk2(0.0f, 0.0f);
    const int ml = (64 - lane) & 63;
    #pragma unroll
    for (int r = 0; r < 4; ++r) {
        float mrA = __shfl(zrA[7 - r], ml), miA = __shfl(ziA[7 - r], ml);
        float mrB = __shfl(zrB[7 - r], ml), miB = __shfl(ziB[7 - r], ml);
        if (lane == 0) {
            mrA = zrA[(8 - r) & 7]; miA = ziA[(8 - r) & 7];
            mrB = zrB[(8 - r) & 7]; miB = ziB[(8 - r) & 7];
        }
        { float ar = zrA[r] + mrA, ai = ziA[r] - miA;
          float br = ziA[r] + miA, bi = zrA[r] - mrA;
          float p0 = (ar * ar + ai * ai) * inv;
          float p1 = (br * br + bi * bi) * inv;
          PA[64 * r + lane] = pkbf(p0, p1);  eA += mk2(p0, p1); }
        { float ar = zrB[r] + mrB, ai = ziB[r] - miB;
          float br = ziB[r] + miB, bi = zrB[r] - mrB;
          float p0 = (ar * ar + ai * ai) * inv;
          float p1 = (br * br + bi * bi) * inv;
          PB[64 * r + lane] = pkbf(p0, p1);  eB += mk2(p0, p1); }
    }
    if (lane == 0) {
        float pA0 = 4.0f * zrA[4] * zrA[4] * inv, pA1 = 4.0f * ziA[4] * ziA[4] * inv;
        float pB0 = 4.0f * zrB[4] * zrB[4] * inv, pB1 = 4.0f * ziB[4] * ziB[4] * inv;
        PA[256] = pkbf(pA0, pA1);  eA += mk2(pA0, pA1);
        PB[256] = pkbf(pB0, pB1);  eB += mk2(pB0, pB1);
    }
#define ERED(E)                                                               \
    E = E + mk2(fdpp<DPP_X1>(E.x),  fdpp<DPP_X1>(E.y));                       \
    E = E + mk2(fdpp<DPP_X2>(E.x),  fdpp<DPP_X2>(E.y));                       \
    E = E + mk2(fswz<SWZ_X4>(E.x),  fswz<SWZ_X4>(E.y));                       \
    E = E + mk2(fdpp<DPP_X8>(E.x),  fdpp<DPP_X8>(E.y));                       \
    E = E + mk2(fswz<SWZ_X16>(E.x), fswz<SWZ_X16>(E.y));                      \
    { uv2 rx = pl32(E.x), ry = pl32(E.y);                                     \
      E = mk2(__builtin_bit_cast(float, rx[0]) + __builtin_bit_cast(float, rx[1]), \
              __builtin_bit_cast(float, ry[0]) + __builtin_bit_cast(float, ry[1])); }
    ERED(eA)
    ERED(eB)
    __builtin_amdgcn_wave_barrier();

    // ---- mel filterbank: lanes 0..26 -> pair0, 32..58 -> pair1 ----
    const int  j  = lane & 31;
    const bool hi = lane >= 32;
    {
        const unsigned* P = hi ? PB : PA;
        v2f fu = mk2(0, 0), fs = mk2(0, 0), fu2 = mk2(0, 0), fs2 = mk2(0, 0);
        if (j <= NFILT) {
            int bA = binsS[j], bZ = binsS[j + 1];
            int i = bA;
            for (; i + 1 < bZ; i += 2) {
                v2f p = unpkbf(P[i]), p2 = unpkbf(P[i + 1]);
                float c0 = (float)(i - bA), c1 = (float)(i + 1 - bA);
                fs  += p;   fu  = pfma(p,  mk2(c0, c0), fu);
                fs2 += p2;  fu2 = pfma(p2, mk2(c1, c1), fu2);
            }
            if (i < bZ) {
                v2f p = unpkbf(P[i]);
                float c0 = (float)(i - bA);
                fs += p;  fu = pfma(p, mk2(c0, c0), fu);
            }
            fs += fs2;  fu += fu2;
            float iw = (bZ > bA) ? 1.0f / (float)(bZ - bA) : 0.0f;
            fu = fu * mk2(iw, iw);
        }
        v2f down = fs - fu;
        v2f dn = mk2(__shfl(down.x, lane + 1), __shfl(down.y, lane + 1));
        if (j < NFILT) {
            v2f ft = fu + dn;
            v2f fv = mk2(__logf(ft.x + EPSF), __logf(ft.y + EPSF));
            if (hi) featBs[w][j] = fv; else featAs[w][j] = fv;
        }
    }
    __builtin_amdgcn_wave_barrier();

    // ---- DCT (lifter pre-folded) + store live frames only ----
    if (j < NUMCEP) {
        const v2f* ft = hi ? featBs[w] : featAs[w];
        v2f a0 = mk2(0, 0), a1 = mk2(0, 0);
        #pragma unroll
        for (int jj = 0; jj < NFILT; jj += 2) {
            float c0 = dctS[j * NFILT + jj], c1 = dctS[j * NFILT + jj + 1];
            a0 = pfma(ft[jj],     mk2(c0, c0), a0);
            a1 = pfma(ft[jj + 1], mk2(c1, c1), a1);
        }
        v2f val = a0 + a1;
        if (j == 0) {
            v2f E = hi ? eB : eA;
            val = mk2(__logf(E.x + EPSF), __logf(E.y + EPSF));
        }
        const int fb = f0 + (hi ? 2 : 0);
        long o0 = ((long)b * NFRAMES + fb) * NUMCEP + j;
        if (fb < nf)     out[o0]          = val.x;   // dead frames zeroed by dead blocks
        if (fb + 1 < nf) out[o0 + NUMCEP] = val.y;
    }
}

extern "C" void kernel_launch(void* const* d_in, const int* in_sizes, int n_in,
                              void* d_out, int out_size, void* d_ws, size_t ws_size,
                              hipStream_t stream) {
    const float* sig     = (const float*)d_in[0];
    const int*   lengths = (const int*)d_in[1];
    float* out = (float*)d_out;

    mfcc_setup_kernel<<<1, 64, 0, stream>>>(lengths, d_ws,
                                            out + (size_t)BATCH * NFRAMES * NUMCEP);

    // 8000 blocks: live-quad blocks compute, remaining blocks zero-fill dead frames
    mfcc_kernel<<<GRID_MAIN, 256, 0, stream>>>(sig, lengths, d_ws, out);
}

// Round 12
// 47.685 us; speedup vs baseline: 1.0998x; 1.0998x over previous
//
#include <hip/hip_runtime.h>
#include <math.h>

#define SRATE   16000
#define FLEN    400
#define STEP    160
#define NFFT    512
#define NBINS   257
#define NFILT   26
#define NUMCEP  13
#define BATCH   64
#define TLEN    320000
#define NFRAMES 1999
#define EPSF    1.1920929e-07f
#define PI_F    3.14159265358979323846f

#define GRID_MAIN 8000

typedef float    v2f __attribute__((ext_vector_type(2)));
typedef unsigned uv2 __attribute__((ext_vector_type(2)));

__device__ __forceinline__ v2f mk2(float a, float b) { v2f v; v.x = a; v.y = b; return v; }
__device__ __forceinline__ v2f pfma(v2f a, v2f b, v2f c) { return __builtin_elementwise_fma(a, b, c); }

// pack two f32 -> 2xbf16, and unpack
__device__ __forceinline__ unsigned pkbf(float a, float b) {
    unsigned ua = __builtin_bit_cast(unsigned, a);
    unsigned ub = __builtin_bit_cast(unsigned, b);
    return ((ua + 0x8000u) >> 16) | ((ub + 0x8000u) & 0xFFFF0000u);
}
__device__ __forceinline__ v2f unpkbf(unsigned u) {
    return mk2(__builtin_bit_cast(float, u << 16),
               __builtin_bit_cast(float, u & 0xFFFF0000u));
}

template<int CTRL>
__device__ __forceinline__ float fdpp(float x) {   // DPP: VALU pipe
    return __builtin_bit_cast(float, __builtin_amdgcn_mov_dpp(
        __builtin_bit_cast(int, x), CTRL, 0xF, 0xF, true));
}
template<int IMM>
__device__ __forceinline__ float fswz(float x) {   // ds_swizzle: DS pipe
    return __builtin_bit_cast(float, __builtin_amdgcn_ds_swizzle(
        __builtin_bit_cast(int, x), IMM));
}
__device__ __forceinline__ float fbp(float x, int idx) {  // ds_bpermute: DS pipe
    return __builtin_bit_cast(float, __builtin_amdgcn_ds_bpermute(
        idx, __builtin_bit_cast(int, x)));
}
__device__ __forceinline__ uv2 pl32(float x) {     // permlane32_swap: VALU pipe
    unsigned u = __builtin_bit_cast(unsigned, x);
    return __builtin_amdgcn_permlane32_swap(u, u, false, false);
}
#if __has_builtin(__builtin_amdgcn_permlane16_swap)
__device__ __forceinline__ float fxor16(float x, bool hi16) {  // VALU pipe
    unsigned u = __builtin_bit_cast(unsigned, x);
    uv2 r = __builtin_amdgcn_permlane16_swap(u, u, false, false);
    return __builtin_bit_cast(float, hi16 ? r[0] : r[1]);
}
#define SH_X16(v) fxor16(v, hi_)
#else
#define SH_X16(v) fswz<0x401F>(v)
#endif

#define DPP_X1   0xB1
#define DPP_X2   0x4E
#define DPP_X8   0x128
#define SWZ_X2   0x081F
#define SWZ_X4   0x101F
#define SWZ_X8   0x201F
#define SWZ_X16  0x401F

// ws layout (int/float-indexed): bins[0..31] | dct[32..369] | qoff[370..434] |
// doff[440..504] | twid[512..2047] (64 lanes x 24 f32)
#define WS_DCT  32
#define WS_QOFF 370
#define WS_DOFF 440
#define WS_TWID 512

// ---------------------------------------------------------------------------
// Setup: mel bins (f64), lifted DCT (f64), nframes output, live-quad prefix
// qoff[65], dead-frame prefix doff[65], per-lane twiddle table (f64-accurate).
// ---------------------------------------------------------------------------
__global__ void mfcc_setup_kernel(const int* __restrict__ lengths,
                                  void* __restrict__ ws,
                                  float* __restrict__ out_nframes) {
    int tid = threadIdx.x;           // 64 threads = 1 wave
    int*   bins = (int*)ws;
    float* dctw = (float*)ws + WS_DCT;
    int*   qoff = (int*)ws + WS_QOFF;
    int*   doff = (int*)ws + WS_DOFF;

    if (tid < 28) {
        double M    = 2595.0 * log10(1.0 + 8000.0 / 700.0);
        double step = M / 27.0;
        double mel  = (tid == 27) ? M : (double)tid * step;
        double hz   = 700.0 * (pow(10.0, mel / 2595.0) - 1.0);
        bins[tid] = (int)floor((double)(NFFT + 1) * hz / (double)SRATE);
    }
    for (int t = tid; t < NUMCEP * NFILT; t += 64) {
        int k = t / NFILT, j = t - k * NFILT;
        double v = cos(M_PI * (double)((2 * j + 1) * k) / (2.0 * (double)NFILT));
        v *= (k == 0) ? 1.0 / sqrt((double)NFILT) : sqrt(2.0 / (double)NFILT);
        double lift = 1.0 + 11.0 * sin(M_PI * (double)k / 22.0);
        dctw[t] = (float)(v * lift);
    }
    // twiddle table: T = e^{-2*pi*i*tid/512}, powers by f64 squaring
    {
        double a = -M_PI * (double)tid / 256.0;
        double tr = cos(a), ti = sin(a);
        float* tw = (float*)ws + WS_TWID + tid * 24;
        tw[0] = (float)tr;  tw[1] = (float)ti;
        double xr = tr, xi = ti;
        #pragma unroll
        for (int k = 1; k < 8; ++k) {
            double nr = xr * xr - xi * xi;
            xi = 2.0 * xr * xi;
            xr = nr;
            tw[2 * k] = (float)xr;  tw[2 * k + 1] = (float)xi;
        }
        const double RH = 0.70710678118654752440;
        tw[16] = (float)(RH * (tr + ti));  tw[17] = (float)(RH * (ti - tr));   // A1
        tw[18] = (float)ti;                tw[19] = (float)(-tr);              // A2
        tw[20] = (float)(RH * (ti - tr));  tw[21] = (float)(-RH * (tr + ti));  // A3
        tw[22] = 0.0f;  tw[23] = 0.0f;
    }
    {
        int len = lengths[tid];
        int nf  = (len <= FLEN) ? 1 : 1 + (len - FLEN + STEP - 1) / STEP;
        out_nframes[tid] = (float)nf;
        int x = (nf + 3) >> 2;                       // live quads for this b
        int d = NFRAMES - nf;                        // dead frames for this b
        #pragma unroll
        for (int off = 1; off < 64; off <<= 1) {
            int y  = __shfl_up(x, off);
            int y2 = __shfl_up(d, off);
            if (tid >= off) { x += y; d += y2; }
        }
        qoff[tid + 1] = x;
        doff[tid + 1] = d;
        if (tid == 0) { qoff[0] = 0; doff[0] = 0; }
    }
}

// ---------------------------------------------------------------------------
// Main kernel: one wave per LIVE frame quad; dead blocks zero-fill dead ceps.
// Pipe-balanced FFT shuffles: x1 DPP (VALU), x2/x4/x8 ds_swizzle (DS),
// x16 permlane16 (VALU), x32 ds_bpermute (DS). Twiddles loaded from table.
// ---------------------------------------------------------------------------
__global__ __launch_bounds__(256)
void mfcc_kernel(const float* __restrict__ sig,
                 const int*   __restrict__ lengths,
                 const void*  __restrict__ ws,
                 float*       __restrict__ out) {
    __shared__ unsigned psA[4][260];     // pair0 pspec, 2xbf16 per bin
    __shared__ unsigned psB[4][260];     // pair1 pspec
    __shared__ v2f featAs[4][28], featBs[4][28];
    __shared__ float dctS[NUMCEP * NFILT];
    __shared__ int   binsS[NFILT + 2];

    const int tid  = threadIdx.x;
    const int lane = tid & 63;
    const int w    = tid >> 6;

    const int* qoffG = (const int*)ws + WS_QOFF;
    const int total = qoffG[64];

    // ---- dead block: zero-fill the dead ceps region, then exit ----
    if ((int)blockIdx.x * 4 >= total) {
        const int* doffG = (const int*)ws + WS_DOFF;
        const int liveBlocks = (total + 3) >> 2;
        const int deadFrames = doffG[64];
        const long deadFloats = (long)deadFrames * NUMCEP;
        const long stride = (long)(GRID_MAIN - liveBlocks) * 256;
        for (long idx = (long)(blockIdx.x - liveBlocks) * 256 + tid;
             idx < deadFloats; idx += stride) {
            int F = (int)(idx / 13);
            int k = (int)(idx - 13L * F);
            int lo = 0, hi = 64;
            #pragma unroll
            for (int it = 0; it < 6; ++it) {
                int mid = (lo + hi) >> 1;
                if (doffG[mid] <= F) lo = mid; else hi = mid;
            }
            int nf2 = NFRAMES - (doffG[lo + 1] - doffG[lo]);
            int f   = nf2 + (F - doffG[lo]);
            out[((long)lo * NFRAMES + f) * NUMCEP + k] = 0.0f;
        }
        return;
    }

    // ---- twiddle table loads (early, latency overlapped) ----
    const float* twg = (const float*)ws + WS_TWID + lane * 24;
    const float4 tq0 = *(const float4*)(twg);
    const float4 tq1 = *(const float4*)(twg + 4);
    const float4 tq2 = *(const float4*)(twg + 8);
    const float4 tq3 = *(const float4*)(twg + 12);
    const float4 tq4 = *(const float4*)(twg + 16);
    const float2 tq5 = *(const float2*)(twg + 20);
    const float T1r = tq0.x, T1i = tq0.y, T2r = tq0.z, T2i = tq0.w;
    const float T4r = tq1.x, T4i = tq1.y, T8r = tq1.z, T8i = tq1.w;
    const float T16r = tq2.x, T16i = tq2.y, T32r = tq2.z, T32i = tq2.w;
    const float T64r = tq3.x, T64i = tq3.y, T128r = tq3.z, T128i = tq3.w;
    const float A1r = tq4.x, A1i = tq4.y, A2r = tq4.z, A2i = tq4.w;
    const float A3r = tq5.x, A3i = tq5.y;
    const int bpidx = (lane ^ 32) << 2;              // ds_bpermute xor32 index

    {
        const int*   binsG = (const int*)ws;
        const float* dctG  = (const float*)ws + WS_DCT;
        for (int t = tid; t < NUMCEP * NFILT; t += 256) dctS[t] = dctG[t];
        if (tid < NFILT + 2) binsS[tid] = binsG[tid];
    }
    __syncthreads();

    // ---- dense live index -> (b, q) via ballot search ----
    const int L = blockIdx.x * 4 + w;
    if (L >= total) return;                          // partial tail block
    int qv = qoffG[lane];
    unsigned long long mm = __ballot(qv <= L);
    const int b  = __popcll(mm) - 1;
    const int q  = L - qoffG[b];
    const int f0 = 4 * q;
    const int len = lengths[b];
    const int nf  = (len <= FLEN) ? 1 : 1 + (len - FLEN + STEP - 1) / STEP;

    const float* s = sig + (long)b * TLEN;
    const int base = f0 * STEP;

    const int B   = (int)(__brev((unsigned)lane) >> 26);   // brev6
    const int i0  = 8 * B;
    const bool liveB = (i0 < FLEN);

    // ---- load + pre-emphasis + mask -> two packed FFT states ----
    v2f Zr0[4], Zi0[4], Zr1[4], Zi1[4];
    const bool fastw = (base >= 1) && (base + 880 <= len);
    if (fastw) {
        float w0[9], w1[9], w2[9], w3[9];
        if (liveB) {
            const float4* sv = (const float4*)(s + base + i0);
            float4 a0 = sv[-1],  a1 = sv[0],   a2 = sv[1];
            float4 b0 = sv[39],  b1 = sv[40],  b2 = sv[41];
            float4 c0 = sv[79],  c1 = sv[80],  c2 = sv[81];
            float4 d0 = sv[119], d1 = sv[120], d2 = sv[121];
#define UNPK(W, q0, q1, q2)                                                   \
            W[0] = q0.w; W[1] = q1.x; W[2] = q1.y; W[3] = q1.z; W[4] = q1.w;  \
            W[5] = q2.x; W[6] = q2.y; W[7] = q2.z; W[8] = q2.w;
            UNPK(w0, a0, a1, a2)
            UNPK(w1, b0, b1, b2)
            UNPK(w2, c0, c1, c2)
            UNPK(w3, d0, d1, d2)
#undef UNPK
        } else {
            #pragma unroll
            for (int j = 0; j < 9; ++j) { w0[j] = w1[j] = w2[j] = w3[j] = 0.0f; }
        }
        #pragma unroll
        for (int m = 0; m < 4; ++m) {
            const int j = (m == 0) ? 0 : (m == 1) ? 4 : (m == 2) ? 2 : 6;  // brev3
            Zr0[m] = mk2(fmaf(-0.97f, w0[j],     w0[j + 1]),
                         fmaf(-0.97f, w0[j + 1], w0[j + 2]));
            Zi0[m] = mk2(fmaf(-0.97f, w1[j],     w1[j + 1]),
                         fmaf(-0.97f, w1[j + 1], w1[j + 2]));
            Zr1[m] = mk2(fmaf(-0.97f, w2[j],     w2[j + 1]),
                         fmaf(-0.97f, w2[j + 1], w2[j + 2]));
            Zi1[m] = mk2(fmaf(-0.97f, w3[j],     w3[j + 1]),
                         fmaf(-0.97f, w3[j + 1], w3[j + 2]));
        }
    } else {
        float w0[9], w1[9], w2[9], w3[9];
        const int tb0 = base + i0 - 1;
        #pragma unroll
        for (int j = 0; j < 9; ++j) {
            int t0 = tb0 + j;
            w0[j] = (liveB && t0 >= 0 && t0 < len) ? s[t0] : 0.0f;
            int t1 = t0 + 160; w1[j] = (liveB && t1 < len) ? s[t1] : 0.0f;
            int t2 = t0 + 320; w2[j] = (liveB && t2 < len) ? s[t2] : 0.0f;
            int t3 = t0 + 480; w3[j] = (liveB && t3 < len) ? s[t3] : 0.0f;
        }
        const int tbe = base + i0;
        #pragma unroll
        for (int m = 0; m < 4; ++m) {
            const int j = (m == 0) ? 0 : (m == 1) ? 4 : (m == 2) ? 2 : 6;
#define ASMW(Wk, OFF, DST)                                                    \
            { float va = fmaf(-0.97f, Wk[j],     Wk[j + 1]);                  \
              float vb = fmaf(-0.97f, Wk[j + 1], Wk[j + 2]);                  \
              bool ma = liveB && (tbe + (OFF) + j)     < len;                 \
              bool mb = liveB && (tbe + (OFF) + j + 1) < len;                 \
              DST = mk2(ma ? va : 0.0f, mb ? vb : 0.0f); }
            ASMW(w0, 0,   Zr0[m])
            ASMW(w1, 160, Zi0[m])
            ASMW(w2, 320, Zr1[m])
            ASMW(w3, 480, Zi1[m])
#undef ASMW
        }
    }

    // ---- cross-lane stage d=1 (both FFTs, interleaved per m): DPP ----
    {
        const float sg = (lane & 1) ? -1.0f : 1.0f;
        const v2f sg2 = mk2(sg, sg);
        #pragma unroll
        for (int m = 0; m < 4; ++m) {
            v2f pr0 = mk2(fdpp<DPP_X1>(Zr0[m].x), fdpp<DPP_X1>(Zr0[m].y));
            v2f pi0 = mk2(fdpp<DPP_X1>(Zi0[m].x), fdpp<DPP_X1>(Zi0[m].y));
            v2f pr1 = mk2(fdpp<DPP_X1>(Zr1[m].x), fdpp<DPP_X1>(Zr1[m].y));
            v2f pi1 = mk2(fdpp<DPP_X1>(Zi1[m].x), fdpp<DPP_X1>(Zi1[m].y));
            Zr0[m] = pfma(sg2, Zr0[m], pr0);
            Zi0[m] = pfma(sg2, Zi0[m], pi0);
            Zr1[m] = pfma(sg2, Zr1[m], pr1);
            Zi1[m] = pfma(sg2, Zi1[m], pi1);
        }
    }

    // ---- cross-lane stages d = 2..32 ----
#define PK_XSTAGE2(d, UR, UI, SH)                                             \
    {                                                                         \
        const bool hi_ = (lane & (d)) != 0;                                   \
        const float ur = hi_ ? (UR) : 1.0f;                                   \
        const float ui = hi_ ? (UI) : 0.0f;                                   \
        const float sg = hi_ ? 1.0f : -1.0f;                                  \
        const v2f ur2 = mk2(ur, ur), ui2 = mk2(ui, ui);                       \
        const v2f nui2 = mk2(-ui, -ui), sg2 = mk2(sg, sg);                    \
        _Pragma("unroll")                                                     \
        for (int m = 0; m < 4; ++m) {                                         \
            v2f tr0 = pfma(Zi0[m], nui2, Zr0[m] * ur2);                       \
            v2f ti0 = pfma(Zi0[m], ur2,  Zr0[m] * ui2);                       \
            v2f tr1 = pfma(Zi1[m], nui2, Zr1[m] * ur2);                       \
            v2f ti1 = pfma(Zi1[m], ur2,  Zr1[m] * ui2);                       \
            v2f pr0 = mk2(SH(tr0.x), SH(tr0.y));                              \
            v2f pi0 = mk2(SH(ti0.x), SH(ti0.y));                              \
            v2f pr1 = mk2(SH(tr1.x), SH(tr1.y));                              \
            v2f pi1 = mk2(SH(ti1.x), SH(ti1.y));                              \
            Zr0[m] = pfma(sg2, pr0, tr0);                                     \
            Zi0[m] = pfma(sg2, pi0, ti0);                                     \
            Zr1[m] = pfma(sg2, pr1, tr1);                                     \
            Zi1[m] = pfma(sg2, pi1, ti1);                                     \
        }                                                                     \
    }
#define SH_X2(v)  fswz<SWZ_X2>(v)
#define SH_X4(v)  fswz<SWZ_X4>(v)
#define SH_X8(v)  fswz<SWZ_X8>(v)
#define SH_X32(v) fbp(v, bpidx)
    PK_XSTAGE2(2,  T128r, T128i, SH_X2)
    PK_XSTAGE2(4,  T64r,  T64i,  SH_X4)
    PK_XSTAGE2(8,  T32r,  T32i,  SH_X8)
    PK_XSTAGE2(16, T16r,  T16i,  SH_X16)
    PK_XSTAGE2(32, T8r,   T8i,   SH_X32)

    // ---- in-register stages d=64, d=128 (both FFTs) ----
#define PBFLY2(A, Bv, WR, WI)                                                 \
    {                                                                         \
        const v2f wr2 = mk2((WR), (WR)), wi2 = mk2((WI), (WI));               \
        const v2f nwi2 = mk2(-(WI), -(WI));                                   \
        v2f tr0 = pfma(Zi0[Bv], nwi2, Zr0[Bv] * wr2);                         \
        v2f ti0 = pfma(Zi0[Bv], wr2,  Zr0[Bv] * wi2);                         \
        v2f tr1 = pfma(Zi1[Bv], nwi2, Zr1[Bv] * wr2);                         \
        v2f ti1 = pfma(Zi1[Bv], wr2,  Zr1[Bv] * wi2);                         \
        Zr0[Bv] = Zr0[A] - tr0;  Zi0[Bv] = Zi0[A] - ti0;                      \
        Zr0[A]  = Zr0[A] + tr0;  Zi0[A]  = Zi0[A] + ti0;                      \
        Zr1[Bv] = Zr1[A] - tr1;  Zi1[Bv] = Zi1[A] - ti1;                      \
        Zr1[A]  = Zr1[A] + tr1;  Zi1[A]  = Zi1[A] + ti1;                      \
    }
    PBFLY2(0, 1, T4r, T4i)
    PBFLY2(2, 3, T4r, T4i)
    PBFLY2(0, 2, T2r, T2i)
    PBFLY2(1, 3, T2i, -T2r)

    // ---- final stage d=256 (both FFTs) ----
    float zrA[8], ziA[8], zrB[8], ziB[8];
    #pragma unroll
    for (int m = 0; m < 4; ++m) {
        const float Wr = (m == 0) ? T1r : (m == 1) ? A1r : (m == 2) ? A2r : A3r;
        const float Wi = (m == 0) ? T1i : (m == 1) ? A1i : (m == 2) ? A2i : A3i;
        { float tr = Zr0[m].y * Wr - Zi0[m].y * Wi;
          float ti = Zr0[m].y * Wi + Zi0[m].y * Wr;
          zrA[m]     = Zr0[m].x + tr;  ziA[m]     = Zi0[m].x + ti;
          zrA[m + 4] = Zr0[m].x - tr;  ziA[m + 4] = Zi0[m].x - ti; }
        { float tr = Zr1[m].y * Wr - Zi1[m].y * Wi;
          float ti = Zr1[m].y * Wi + Zi1[m].y * Wr;
          zrB[m]     = Zr1[m].x + tr;  ziB[m]     = Zi1[m].x + ti;
          zrB[m + 4] = Zr1[m].x - tr;  ziB[m + 4] = Zi1[m].x - ti; }
    }

    // ---- unpack 2x2 real spectra + power + energy (pspec -> 2xbf16 LDS) ----
    unsigned* PA = psA[w];
    unsigned* PB = psB[w];
    const float inv = 1.0f / (4.0f * (float)NFFT);
    v2f eA = mk2(0.0f, 0.0f), eB = mk2(0.0f, 0.0f);
    const int ml = (64 - lane) & 63;
    #pragma unroll
    for (int r = 0; r < 4; ++r) {
        float mrA = __shfl(zrA[7 - r], ml), miA = __shfl(ziA[7 - r], ml);
        float mrB = __shfl(zrB[7 - r], ml), miB = __shfl(ziB[7 - r], ml);
        if (lane == 0) {
            mrA = zrA[(8 - r) & 7]; miA = ziA[(8 - r) & 7];
            mrB = zrB[(8 - r) & 7]; miB = ziB[(8 - r) & 7];
        }
        { float ar = zrA[r] + mrA, ai = ziA[r] - miA;
          float br = ziA[r] + miA, bi = zrA[r] - mrA;
          float p0 = (ar * ar + ai * ai) * inv;
          float p1 = (br * br + bi * bi) * inv;
          PA[64 * r + lane] = pkbf(p0, p1);  eA += mk2(p0, p1); }
        { float ar = zrB[r] + mrB, ai = ziB[r] - miB;
          float br = ziB[r] + miB, bi = zrB[r] - mrB;
          float p0 = (ar * ar + ai * ai) * inv;
          float p1 = (br * br + bi * bi) * inv;
          PB[64 * r + lane] = pkbf(p0, p1);  eB += mk2(p0, p1); }
    }
    if (lane == 0) {
        float pA0 = 4.0f * zrA[4] * zrA[4] * inv, pA1 = 4.0f * ziA[4] * ziA[4] * inv;
        float pB0 = 4.0f * zrB[4] * zrB[4] * inv, pB1 = 4.0f * ziB[4] * ziB[4] * inv;
        PA[256] = pkbf(pA0, pA1);  eA += mk2(pA0, pA1);
        PB[256] = pkbf(pB0, pB1);  eB += mk2(pB0, pB1);
    }
#define ERED(E)                                                               \
    E = E + mk2(fdpp<DPP_X1>(E.x),  fdpp<DPP_X1>(E.y));                       \
    E = E + mk2(fdpp<DPP_X2>(E.x),  fdpp<DPP_X2>(E.y));                       \
    E = E + mk2(fswz<SWZ_X4>(E.x),  fswz<SWZ_X4>(E.y));                       \
    E = E + mk2(fdpp<DPP_X8>(E.x),  fdpp<DPP_X8>(E.y));                       \
    E = E + mk2(fswz<SWZ_X16>(E.x), fswz<SWZ_X16>(E.y));                      \
    { uv2 rx = pl32(E.x), ry = pl32(E.y);                                     \
      E = mk2(__builtin_bit_cast(float, rx[0]) + __builtin_bit_cast(float, rx[1]), \
              __builtin_bit_cast(float, ry[0]) + __builtin_bit_cast(float, ry[1])); }
    ERED(eA)
    ERED(eB)
    __builtin_amdgcn_wave_barrier();

    // ---- mel filterbank: lanes 0..26 -> pair0, 32..58 -> pair1 ----
    const int  j  = lane & 31;
    const bool hi = lane >= 32;
    {
        const unsigned* P = hi ? PB : PA;
        v2f fu = mk2(0, 0), fs = mk2(0, 0), fu2 = mk2(0, 0), fs2 = mk2(0, 0);
        if (j <= NFILT) {
            int bA = binsS[j], bZ = binsS[j + 1];
            int i = bA;
            for (; i + 1 < bZ; i += 2) {
                v2f p = unpkbf(P[i]), p2 = unpkbf(P[i + 1]);
                float c0 = (float)(i - bA), c1 = (float)(i + 1 - bA);
                fs  += p;   fu  = pfma(p,  mk2(c0, c0), fu);
                fs2 += p2;  fu2 = pfma(p2, mk2(c1, c1), fu2);
            }
            if (i < bZ) {
                v2f p = unpkbf(P[i]);
                float c0 = (float)(i - bA);
                fs += p;  fu = pfma(p, mk2(c0, c0), fu);
            }
            fs += fs2;  fu += fu2;
            float iw = (bZ > bA) ? 1.0f / (float)(bZ - bA) : 0.0f;
            fu = fu * mk2(iw, iw);
        }
        v2f down = fs - fu;
        v2f dn = mk2(__shfl(down.x, lane + 1), __shfl(down.y, lane + 1));
        if (j < NFILT) {
            v2f ft = fu + dn;
            v2f fv = mk2(__logf(ft.x + EPSF), __logf(ft.y + EPSF));
            if (hi) featBs[w][j] = fv; else featAs[w][j] = fv;
        }
    }
    __builtin_amdgcn_wave_barrier();

    // ---- DCT (lifter pre-folded) + store live frames only ----
    if (j < NUMCEP) {
        const v2f* ft = hi ? featBs[w] : featAs[w];
        v2f a0 = mk2(0, 0), a1 = mk2(0, 0);
        #pragma unroll
        for (int jj = 0; jj < NFILT; jj += 2) {
            float c0 = dctS[j * NFILT + jj], c1 = dctS[j * NFILT + jj + 1];
            a0 = pfma(ft[jj],     mk2(c0, c0), a0);
            a1 = pfma(ft[jj + 1], mk2(c1, c1), a1);
        }
        v2f val = a0 + a1;
        if (j == 0) {
            v2f E = hi ? eB : eA;
            val = mk2(__logf(E.x + EPSF), __logf(E.y + EPSF));
        }
        const int fb = f0 + (hi ? 2 : 0);
        long o0 = ((long)b * NFRAMES + fb) * NUMCEP + j;
        if (fb < nf)     out[o0]          = val.x;   // dead frames zeroed by dead blocks
        if (fb + 1 < nf) out[o0 + NUMCEP] = val.y;
    }
}

extern "C" void kernel_launch(void* const* d_in, const int* in_sizes, int n_in,
                              void* d_out, int out_size, void* d_ws, size_t ws_size,
                              hipStream_t stream) {
    const float* sig     = (const float*)d_in[0];
    const int*   lengths = (const int*)d_in[1];
    float* out = (float*)d_out;

    mfcc_setup_kernel<<<1, 64, 0, stream>>>(lengths, d_ws,
                                            out + (size_t)BATCH * NFRAMES * NUMCEP);

    // 8000 blocks: live-quad blocks compute, remaining blocks zero-fill dead frames
    mfcc_kernel<<<GRID_MAIN, 256, 0, stream>>>(sig, lengths, d_ws, out);
}

// Round 13
// 46.518 us; speedup vs baseline: 1.1274x; 1.0251x over previous
//
#include <hip/hip_runtime.h>
#include <math.h>

#define SRATE   16000
#define FLEN    400
#define STEP    160
#define NFFT    512
#define NBINS   257
#define NFILT   26
#define NUMCEP  13
#define BATCH   64
#define TLEN    320000
#define NFRAMES 1999
#define EPSF    1.1920929e-07f
#define PI_F    3.14159265358979323846f

#define GRID_MAIN 8000

typedef float    v2f __attribute__((ext_vector_type(2)));
typedef unsigned uv2 __attribute__((ext_vector_type(2)));

__device__ __forceinline__ v2f mk2(float a, float b) { v2f v; v.x = a; v.y = b; return v; }
__device__ __forceinline__ v2f pfma(v2f a, v2f b, v2f c) { return __builtin_elementwise_fma(a, b, c); }

template<int CTRL>
__device__ __forceinline__ float fdpp(float x) {   // DPP: VALU pipe
    return __builtin_bit_cast(float, __builtin_amdgcn_mov_dpp(
        __builtin_bit_cast(int, x), CTRL, 0xF, 0xF, true));
}
template<int IMM>
__device__ __forceinline__ float fswz(float x) {   // ds_swizzle: DS pipe
    return __builtin_bit_cast(float, __builtin_amdgcn_ds_swizzle(
        __builtin_bit_cast(int, x), IMM));
}
__device__ __forceinline__ float fbp(float x, int idx) {  // ds_bpermute: DS pipe
    return __builtin_bit_cast(float, __builtin_amdgcn_ds_bpermute(
        idx, __builtin_bit_cast(int, x)));
}
__device__ __forceinline__ uv2 pl32(float x) {     // permlane32_swap: VALU pipe
    unsigned u = __builtin_bit_cast(unsigned, x);
    return __builtin_amdgcn_permlane32_swap(u, u, false, false);
}
#if __has_builtin(__builtin_amdgcn_permlane16_swap)
__device__ __forceinline__ float fxor16(float x, bool hi16) {  // VALU pipe
    unsigned u = __builtin_bit_cast(unsigned, x);
    uv2 r = __builtin_amdgcn_permlane16_swap(u, u, false, false);
    return __builtin_bit_cast(float, hi16 ? r[0] : r[1]);
}
#define SH_X16(v) fxor16(v, hi_)
#else
#define SH_X16(v) fswz<0x401F>(v)
#endif

#define DPP_X1   0xB1
#define DPP_X2   0x4E
#define DPP_X8   0x128
#define SWZ_X2   0x081F
#define SWZ_X4   0x101F
#define SWZ_X8   0x201F
#define SWZ_X16  0x401F

// ws layout (int/float-indexed): bins[0..31] | dct[32..369] | qoff[370..434] |
// doff[440..504] | twid[512..2047] (64 lanes x 24 f32)
#define WS_DCT  32
#define WS_QOFF 370
#define WS_DOFF 440
#define WS_TWID 512

// ---------------------------------------------------------------------------
// Setup: mel bins (f64), lifted DCT (f64), nframes output, live-quad prefix
// qoff[65], dead-frame prefix doff[65], per-lane twiddle table (f64-accurate).
// ---------------------------------------------------------------------------
__global__ void mfcc_setup_kernel(const int* __restrict__ lengths,
                                  void* __restrict__ ws,
                                  float* __restrict__ out_nframes) {
    int tid = threadIdx.x;           // 64 threads = 1 wave
    int*   bins = (int*)ws;
    float* dctw = (float*)ws + WS_DCT;
    int*   qoff = (int*)ws + WS_QOFF;
    int*   doff = (int*)ws + WS_DOFF;

    if (tid < 28) {
        double M    = 2595.0 * log10(1.0 + 8000.0 / 700.0);
        double step = M / 27.0;
        double mel  = (tid == 27) ? M : (double)tid * step;
        double hz   = 700.0 * (pow(10.0, mel / 2595.0) - 1.0);
        bins[tid] = (int)floor((double)(NFFT + 1) * hz / (double)SRATE);
    }
    for (int t = tid; t < NUMCEP * NFILT; t += 64) {
        int k = t / NFILT, j = t - k * NFILT;
        double v = cos(M_PI * (double)((2 * j + 1) * k) / (2.0 * (double)NFILT));
        v *= (k == 0) ? 1.0 / sqrt((double)NFILT) : sqrt(2.0 / (double)NFILT);
        double lift = 1.0 + 11.0 * sin(M_PI * (double)k / 22.0);
        dctw[t] = (float)(v * lift);
    }
    // twiddle table: T = e^{-2*pi*i*tid/512}, powers by f64 squaring
    {
        double a = -M_PI * (double)tid / 256.0;
        double tr = cos(a), ti = sin(a);
        float* tw = (float*)ws + WS_TWID + tid * 24;
        tw[0] = (float)tr;  tw[1] = (float)ti;
        double xr = tr, xi = ti;
        #pragma unroll
        for (int k = 1; k < 8; ++k) {
            double nr = xr * xr - xi * xi;
            xi = 2.0 * xr * xi;
            xr = nr;
            tw[2 * k] = (float)xr;  tw[2 * k + 1] = (float)xi;
        }
        const double RH = 0.70710678118654752440;
        tw[16] = (float)(RH * (tr + ti));  tw[17] = (float)(RH * (ti - tr));   // A1
        tw[18] = (float)ti;                tw[19] = (float)(-tr);              // A2
        tw[20] = (float)(RH * (ti - tr));  tw[21] = (float)(-RH * (tr + ti));  // A3
        tw[22] = 0.0f;  tw[23] = 0.0f;
    }
    {
        int len = lengths[tid];
        int nf  = (len <= FLEN) ? 1 : 1 + (len - FLEN + STEP - 1) / STEP;
        out_nframes[tid] = (float)nf;
        int x = (nf + 3) >> 2;                       // live quads for this b
        int d = NFRAMES - nf;                        // dead frames for this b
        #pragma unroll
        for (int off = 1; off < 64; off <<= 1) {
            int y  = __shfl_up(x, off);
            int y2 = __shfl_up(d, off);
            if (tid >= off) { x += y; d += y2; }
        }
        qoff[tid + 1] = x;
        doff[tid + 1] = d;
        if (tid == 0) { qoff[0] = 0; doff[0] = 0; }
    }
}

// ---------------------------------------------------------------------------
// Main kernel: one wave per LIVE frame quad; dead blocks zero-fill dead ceps.
// f32 pspec (bf16 detour reverted: R11 regression), float4-paired filterbank
// loads, width-balanced filterbank (lanes 27..31 split the 5 widest filters).
// ---------------------------------------------------------------------------
__global__ __launch_bounds__(256)
void mfcc_kernel(const float* __restrict__ sig,
                 const int*   __restrict__ lengths,
                 const void*  __restrict__ ws,
                 float*       __restrict__ out) {
    __shared__ v2f psA[4][260];          // pair0 pspec (frames f0,f0+1 packed)
    __shared__ v2f psB[4][260];          // pair1 pspec
    __shared__ v2f featAs[4][28], featBs[4][28];
    __shared__ float dctS[NUMCEP * NFILT];
    __shared__ int   binsS[NFILT + 2];

    const int tid  = threadIdx.x;
    const int lane = tid & 63;
    const int w    = tid >> 6;

    const int* qoffG = (const int*)ws + WS_QOFF;
    const int total = qoffG[64];

    // ---- dead block: zero-fill the dead ceps region, then exit ----
    if ((int)blockIdx.x * 4 >= total) {
        const int* doffG = (const int*)ws + WS_DOFF;
        const int liveBlocks = (total + 3) >> 2;
        const int deadFrames = doffG[64];
        const long deadFloats = (long)deadFrames * NUMCEP;
        const long stride = (long)(GRID_MAIN - liveBlocks) * 256;
        for (long idx = (long)(blockIdx.x - liveBlocks) * 256 + tid;
             idx < deadFloats; idx += stride) {
            int F = (int)(idx / 13);
            int k = (int)(idx - 13L * F);
            int lo = 0, hi = 64;
            #pragma unroll
            for (int it = 0; it < 6; ++it) {
                int mid = (lo + hi) >> 1;
                if (doffG[mid] <= F) lo = mid; else hi = mid;
            }
            int nf2 = NFRAMES - (doffG[lo + 1] - doffG[lo]);
            int f   = nf2 + (F - doffG[lo]);
            out[((long)lo * NFRAMES + f) * NUMCEP + k] = 0.0f;
        }
        return;
    }

    // ---- twiddle table loads (early, latency overlapped) ----
    const float* twg = (const float*)ws + WS_TWID + lane * 24;
    const float4 tq0 = *(const float4*)(twg);
    const float4 tq1 = *(const float4*)(twg + 4);
    const float4 tq2 = *(const float4*)(twg + 8);
    const float4 tq3 = *(const float4*)(twg + 12);
    const float4 tq4 = *(const float4*)(twg + 16);
    const float2 tq5 = *(const float2*)(twg + 20);
    const float T1r = tq0.x, T1i = tq0.y, T2r = tq0.z, T2i = tq0.w;
    const float T4r = tq1.x, T4i = tq1.y, T8r = tq1.z, T8i = tq1.w;
    const float T16r = tq2.x, T16i = tq2.y, T32r = tq2.z, T32i = tq2.w;
    const float T64r = tq3.x, T64i = tq3.y, T128r = tq3.z, T128i = tq3.w;
    const float A1r = tq4.x, A1i = tq4.y, A2r = tq4.z, A2i = tq4.w;
    const float A3r = tq5.x, A3i = tq5.y;
    const int bpidx = (lane ^ 32) << 2;              // ds_bpermute xor32 index

    {
        const int*   binsG = (const int*)ws;
        const float* dctG  = (const float*)ws + WS_DCT;
        for (int t = tid; t < NUMCEP * NFILT; t += 256) dctS[t] = dctG[t];
        if (tid < NFILT + 2) binsS[tid] = binsG[tid];
    }
    __syncthreads();

    // ---- dense live index -> (b, q) via ballot search ----
    const int L = blockIdx.x * 4 + w;
    if (L >= total) return;                          // partial tail block
    int qv = qoffG[lane];
    unsigned long long mm = __ballot(qv <= L);
    const int b  = __popcll(mm) - 1;
    const int q  = L - qoffG[b];
    const int f0 = 4 * q;
    const int len = lengths[b];
    const int nf  = (len <= FLEN) ? 1 : 1 + (len - FLEN + STEP - 1) / STEP;

    const float* s = sig + (long)b * TLEN;
    const int base = f0 * STEP;

    const int B   = (int)(__brev((unsigned)lane) >> 26);   // brev6
    const int i0  = 8 * B;
    const bool liveB = (i0 < FLEN);

    // ---- load + pre-emphasis + mask -> two packed FFT states ----
    v2f Zr0[4], Zi0[4], Zr1[4], Zi1[4];
    const bool fastw = (base >= 1) && (base + 880 <= len);
    if (fastw) {
        float w0[9], w1[9], w2[9], w3[9];
        if (liveB) {
            const float4* sv = (const float4*)(s + base + i0);
            float4 a0 = sv[-1],  a1 = sv[0],   a2 = sv[1];
            float4 b0 = sv[39],  b1 = sv[40],  b2 = sv[41];
            float4 c0 = sv[79],  c1 = sv[80],  c2 = sv[81];
            float4 d0 = sv[119], d1 = sv[120], d2 = sv[121];
#define UNPK(W, q0, q1, q2)                                                   \
            W[0] = q0.w; W[1] = q1.x; W[2] = q1.y; W[3] = q1.z; W[4] = q1.w;  \
            W[5] = q2.x; W[6] = q2.y; W[7] = q2.z; W[8] = q2.w;
            UNPK(w0, a0, a1, a2)
            UNPK(w1, b0, b1, b2)
            UNPK(w2, c0, c1, c2)
            UNPK(w3, d0, d1, d2)
#undef UNPK
        } else {
            #pragma unroll
            for (int j = 0; j < 9; ++j) { w0[j] = w1[j] = w2[j] = w3[j] = 0.0f; }
        }
        #pragma unroll
        for (int m = 0; m < 4; ++m) {
            const int j = (m == 0) ? 0 : (m == 1) ? 4 : (m == 2) ? 2 : 6;  // brev3
            Zr0[m] = mk2(fmaf(-0.97f, w0[j],     w0[j + 1]),
                         fmaf(-0.97f, w0[j + 1], w0[j + 2]));
            Zi0[m] = mk2(fmaf(-0.97f, w1[j],     w1[j + 1]),
                         fmaf(-0.97f, w1[j + 1], w1[j + 2]));
            Zr1[m] = mk2(fmaf(-0.97f, w2[j],     w2[j + 1]),
                         fmaf(-0.97f, w2[j + 1], w2[j + 2]));
            Zi1[m] = mk2(fmaf(-0.97f, w3[j],     w3[j + 1]),
                         fmaf(-0.97f, w3[j + 1], w3[j + 2]));
        }
    } else {
        float w0[9], w1[9], w2[9], w3[9];
        const int tb0 = base + i0 - 1;
        #pragma unroll
        for (int j = 0; j < 9; ++j) {
            int t0 = tb0 + j;
            w0[j] = (liveB && t0 >= 0 && t0 < len) ? s[t0] : 0.0f;
            int t1 = t0 + 160; w1[j] = (liveB && t1 < len) ? s[t1] : 0.0f;
            int t2 = t0 + 320; w2[j] = (liveB && t2 < len) ? s[t2] : 0.0f;
            int t3 = t0 + 480; w3[j] = (liveB && t3 < len) ? s[t3] : 0.0f;
        }
        const int tbe = base + i0;
        #pragma unroll
        for (int m = 0; m < 4; ++m) {
            const int j = (m == 0) ? 0 : (m == 1) ? 4 : (m == 2) ? 2 : 6;
#define ASMW(Wk, OFF, DST)                                                    \
            { float va = fmaf(-0.97f, Wk[j],     Wk[j + 1]);                  \
              float vb = fmaf(-0.97f, Wk[j + 1], Wk[j + 2]);                  \
              bool ma = liveB && (tbe + (OFF) + j)     < len;                 \
              bool mb = liveB && (tbe + (OFF) + j + 1) < len;                 \
              DST = mk2(ma ? va : 0.0f, mb ? vb : 0.0f); }
            ASMW(w0, 0,   Zr0[m])
            ASMW(w1, 160, Zi0[m])
            ASMW(w2, 320, Zr1[m])
            ASMW(w3, 480, Zi1[m])
#undef ASMW
        }
    }

    // ---- cross-lane stage d=1 (both FFTs, interleaved per m): DPP ----
    {
        const float sg = (lane & 1) ? -1.0f : 1.0f;
        const v2f sg2 = mk2(sg, sg);
        #pragma unroll
        for (int m = 0; m < 4; ++m) {
            v2f pr0 = mk2(fdpp<DPP_X1>(Zr0[m].x), fdpp<DPP_X1>(Zr0[m].y));
            v2f pi0 = mk2(fdpp<DPP_X1>(Zi0[m].x), fdpp<DPP_X1>(Zi0[m].y));
            v2f pr1 = mk2(fdpp<DPP_X1>(Zr1[m].x), fdpp<DPP_X1>(Zr1[m].y));
            v2f pi1 = mk2(fdpp<DPP_X1>(Zi1[m].x), fdpp<DPP_X1>(Zi1[m].y));
            Zr0[m] = pfma(sg2, Zr0[m], pr0);
            Zi0[m] = pfma(sg2, Zi0[m], pi0);
            Zr1[m] = pfma(sg2, Zr1[m], pr1);
            Zi1[m] = pfma(sg2, Zi1[m], pi1);
        }
    }

    // ---- cross-lane stages d = 2..32 ----
#define PK_XSTAGE2(d, UR, UI, SH)                                             \
    {                                                                         \
        const bool hi_ = (lane & (d)) != 0;                                   \
        const float ur = hi_ ? (UR) : 1.0f;                                   \
        const float ui = hi_ ? (UI) : 0.0f;                                   \
        const float sg = hi_ ? 1.0f : -1.0f;                                  \
        const v2f ur2 = mk2(ur, ur), ui2 = mk2(ui, ui);                       \
        const v2f nui2 = mk2(-ui, -ui), sg2 = mk2(sg, sg);                    \
        _Pragma("unroll")                                                     \
        for (int m = 0; m < 4; ++m) {                                         \
            v2f tr0 = pfma(Zi0[m], nui2, Zr0[m] * ur2);                       \
            v2f ti0 = pfma(Zi0[m], ur2,  Zr0[m] * ui2);                       \
            v2f tr1 = pfma(Zi1[m], nui2, Zr1[m] * ur2);                       \
            v2f ti1 = pfma(Zi1[m], ur2,  Zr1[m] * ui2);                       \
            v2f pr0 = mk2(SH(tr0.x), SH(tr0.y));                              \
            v2f pi0 = mk2(SH(ti0.x), SH(ti0.y));                              \
            v2f pr1 = mk2(SH(tr1.x), SH(tr1.y));                              \
            v2f pi1 = mk2(SH(ti1.x), SH(ti1.y));                              \
            Zr0[m] = pfma(sg2, pr0, tr0);                                     \
            Zi0[m] = pfma(sg2, pi0, ti0);                                     \
            Zr1[m] = pfma(sg2, pr1, tr1);                                     \
            Zi1[m] = pfma(sg2, pi1, ti1);                                     \
        }                                                                     \
    }
#define SH_X2(v)  fswz<SWZ_X2>(v)
#define SH_X4(v)  fswz<SWZ_X4>(v)
#define SH_X8(v)  fswz<SWZ_X8>(v)
#define SH_X32(v) fbp(v, bpidx)
    PK_XSTAGE2(2,  T128r, T128i, SH_X2)
    PK_XSTAGE2(4,  T64r,  T64i,  SH_X4)
    PK_XSTAGE2(8,  T32r,  T32i,  SH_X8)
    PK_XSTAGE2(16, T16r,  T16i,  SH_X16)
    PK_XSTAGE2(32, T8r,   T8i,   SH_X32)

    // ---- in-register stages d=64, d=128 (both FFTs) ----
#define PBFLY2(A, Bv, WR, WI)                                                 \
    {                                                                         \
        const v2f wr2 = mk2((WR), (WR)), wi2 = mk2((WI), (WI));               \
        const v2f nwi2 = mk2(-(WI), -(WI));                                   \
        v2f tr0 = pfma(Zi0[Bv], nwi2, Zr0[Bv] * wr2);                         \
        v2f ti0 = pfma(Zi0[Bv], wr2,  Zr0[Bv] * wi2);                         \
        v2f tr1 = pfma(Zi1[Bv], nwi2, Zr1[Bv] * wr2);                         \
        v2f ti1 = pfma(Zi1[Bv], wr2,  Zr1[Bv] * wi2);                         \
        Zr0[Bv] = Zr0[A] - tr0;  Zi0[Bv] = Zi0[A] - ti0;                      \
        Zr0[A]  = Zr0[A] + tr0;  Zi0[A]  = Zi0[A] + ti0;                      \
        Zr1[Bv] = Zr1[A] - tr1;  Zi1[Bv] = Zi1[A] - ti1;                      \
        Zr1[A]  = Zr1[A] + tr1;  Zi1[A]  = Zi1[A] + ti1;                      \
    }
    PBFLY2(0, 1, T4r, T4i)
    PBFLY2(2, 3, T4r, T4i)
    PBFLY2(0, 2, T2r, T2i)
    PBFLY2(1, 3, T2i, -T2r)

    // ---- final stage d=256 (both FFTs) ----
    float zrA[8], ziA[8], zrB[8], ziB[8];
    #pragma unroll
    for (int m = 0; m < 4; ++m) {
        const float Wr = (m == 0) ? T1r : (m == 1) ? A1r : (m == 2) ? A2r : A3r;
        const float Wi = (m == 0) ? T1i : (m == 1) ? A1i : (m == 2) ? A2i : A3i;
        { float tr = Zr0[m].y * Wr - Zi0[m].y * Wi;
          float ti = Zr0[m].y * Wi + Zi0[m].y * Wr;
          zrA[m]     = Zr0[m].x + tr;  ziA[m]     = Zi0[m].x + ti;
          zrA[m + 4] = Zr0[m].x - tr;  ziA[m + 4] = Zi0[m].x - ti; }
        { float tr = Zr1[m].y * Wr - Zi1[m].y * Wi;
          float ti = Zr1[m].y * Wi + Zi1[m].y * Wr;
          zrB[m]     = Zr1[m].x + tr;  ziB[m]     = Zi1[m].x + ti;
          zrB[m + 4] = Zr1[m].x - tr;  ziB[m + 4] = Zi1[m].x - ti; }
    }

    // ---- unpack 2x2 real spectra + power + energy (f32 v2f pspec) ----
    v2f* PA = psA[w];
    v2f* PB = psB[w];
    const float inv = 1.0f / (4.0f * (float)NFFT);
    v2f eA = mk2(0.0f, 0.0f), eB = mk2(0.0f, 0.0f);
    const int ml = (64 - lane) & 63;
    #pragma unroll
    for (int r = 0; r < 4; ++r) {
        float mrA = __shfl(zrA[7 - r], ml), miA = __shfl(ziA[7 - r], ml);
        float mrB = __shfl(zrB[7 - r], ml), miB = __shfl(ziB[7 - r], ml);
        if (lane == 0) {
            mrA = zrA[(8 - r) & 7]; miA = ziA[(8 - r) & 7];
            mrB = zrB[(8 - r) & 7]; miB = ziB[(8 - r) & 7];
        }
        { float ar = zrA[r] + mrA, ai = ziA[r] - miA;
          float br = ziA[r] + miA, bi = zrA[r] - mrA;
          v2f p = mk2((ar * ar + ai * ai) * inv, (br * br + bi * bi) * inv);
          PA[64 * r + lane] = p;  eA += p; }
        { float ar = zrB[r] + mrB, ai = ziB[r] - miB;
          float br = ziB[r] + miB, bi = zrB[r] - mrB;
          v2f p = mk2((ar * ar + ai * ai) * inv, (br * br + bi * bi) * inv);
          PB[64 * r + lane] = p;  eB += p; }
    }
    if (lane == 0) {
        v2f pA = mk2(4.0f * zrA[4] * zrA[4] * inv, 4.0f * ziA[4] * ziA[4] * inv);
        v2f pB = mk2(4.0f * zrB[4] * zrB[4] * inv, 4.0f * ziB[4] * ziB[4] * inv);
        PA[256] = pA;  eA += pA;
        PB[256] = pB;  eB += pB;
    }
#define ERED(E)                                                               \
    E = E + mk2(fdpp<DPP_X1>(E.x),  fdpp<DPP_X1>(E.y));                       \
    E = E + mk2(fdpp<DPP_X2>(E.x),  fdpp<DPP_X2>(E.y));                       \
    E = E + mk2(fswz<SWZ_X4>(E.x),  fswz<SWZ_X4>(E.y));                       \
    E = E + mk2(fdpp<DPP_X8>(E.x),  fdpp<DPP_X8>(E.y));                       \
    E = E + mk2(fswz<SWZ_X16>(E.x), fswz<SWZ_X16>(E.y));                      \
    { uv2 rx = pl32(E.x), ry = pl32(E.y);                                     \
      E = mk2(__builtin_bit_cast(float, rx[0]) + __builtin_bit_cast(float, rx[1]), \
              __builtin_bit_cast(float, ry[0]) + __builtin_bit_cast(float, ry[1])); }
    ERED(eA)
    ERED(eB)
    __builtin_amdgcn_wave_barrier();

    // ---- mel filterbank, width-balanced:
    //      lanes 0..26  -> interval j (front half for j >= 22)
    //      lanes 27..31 -> back half of interval j-5 (the 5 widest)
    const int  j  = lane & 31;
    const bool hi = lane >= 32;
    {
        const v2f* P = hi ? PB : PA;
        const bool helper = (j > NFILT);             // lanes 27..31
        const int  itv    = helper ? (j - 5) : j;    // helper -> 22..26
        v2f fu = mk2(0, 0), fs = mk2(0, 0), fu2 = mk2(0, 0), fs2 = mk2(0, 0);
        if (j < 32 && itv <= NFILT) {
            const int bA = binsS[itv], bZ = binsS[itv + 1];
            const int mid = (bA + bZ) >> 1;
            const bool split = (itv >= 22);
            int i  = split ? (helper ? mid : bA) : bA;
            int ie = split ? (helper ? bZ  : mid) : bZ;
            if (i < ie && (i & 1)) {                 // odd head -> b64
                v2f p = P[i];
                float c = (float)(i - bA);
                fs += p;  fu = pfma(p, mk2(c, c), fu);
                ++i;
            }
            for (; i + 1 < ie; i += 2) {             // paired -> ds_read_b128
                float4 qq = *(const float4*)&P[i];
                v2f p  = mk2(qq.x, qq.y), p2 = mk2(qq.z, qq.w);
                float c0 = (float)(i - bA), c1 = (float)(i + 1 - bA);
                fs  += p;   fu  = pfma(p,  mk2(c0, c0), fu);
                fs2 += p2;  fu2 = pfma(p2, mk2(c1, c1), fu2);
            }
            if (i < ie) {                            // tail -> b64
                v2f p = P[i];
                float c = (float)(i - bA);
                fs += p;  fu = pfma(p, mk2(c, c), fu);
            }
            fs += fs2;  fu += fu2;
        }
        // owners 22..26 pull the helpers' partial sums from lane+5
        {
            v2f fsH = mk2(__shfl(fs.x, lane + 5), __shfl(fs.y, lane + 5));
            v2f fuH = mk2(__shfl(fu.x, lane + 5), __shfl(fu.y, lane + 5));
            if (!helper && itv >= 22) { fs += fsH; fu += fuH; }
        }
        {
            const int bA = binsS[itv], bZ = binsS[itv + 1];
            float iw = (bZ > bA) ? 1.0f / (float)(bZ - bA) : 0.0f;
            fu = fu * mk2(iw, iw);
        }
        v2f down = fs - fu;
        v2f dn = mk2(__shfl(down.x, lane + 1), __shfl(down.y, lane + 1));
        if (!helper && j < NFILT) {
            v2f ft = fu + dn;
            v2f fv = mk2(__logf(ft.x + EPSF), __logf(ft.y + EPSF));
            if (hi) featBs[w][j] = fv; else featAs[w][j] = fv;
        }
    }
    __builtin_amdgcn_wave_barrier();

    // ---- DCT (lifter pre-folded) + store live frames only ----
    if (j < NUMCEP) {
        const v2f* ft = hi ? featBs[w] : featAs[w];
        v2f a0 = mk2(0, 0), a1 = mk2(0, 0);
        #pragma unroll
        for (int jj = 0; jj < NFILT; jj += 2) {
            float c0 = dctS[j * NFILT + jj], c1 = dctS[j * NFILT + jj + 1];
            a0 = pfma(ft[jj],     mk2(c0, c0), a0);
            a1 = pfma(ft[jj + 1], mk2(c1, c1), a1);
        }
        v2f val = a0 + a1;
        if (j == 0) {
            v2f E = hi ? eB : eA;
            val = mk2(__logf(E.x + EPSF), __logf(E.y + EPSF));
        }
        const int fb = f0 + (hi ? 2 : 0);
        long o0 = ((long)b * NFRAMES + fb) * NUMCEP + j;
        if (fb < nf)     out[o0]          = val.x;   // dead frames zeroed by dead blocks
        if (fb + 1 < nf) out[o0 + NUMCEP] = val.y;
    }
}

extern "C" void kernel_launch(void* const* d_in, const int* in_sizes, int n_in,
                              void* d_out, int out_size, void* d_ws, size_t ws_size,
                              hipStream_t stream) {
    const float* sig     = (const float*)d_in[0];
    const int*   lengths = (const int*)d_in[1];
    float* out = (float*)d_out;

    mfcc_setup_kernel<<<1, 64, 0, stream>>>(lengths, d_ws,
                                            out + (size_t)BATCH * NFRAMES * NUMCEP);

    // 8000 blocks: live-quad blocks compute, remaining blocks zero-fill dead frames
    mfcc_kernel<<<GRID_MAIN, 256, 0, stream>>>(sig, lengths, d_ws, out);
}